// Round 1
// baseline (1504.310 us; speedup 1.0000x reference)
//
#include <hip/hip_runtime.h>
#include <math.h>

typedef _Float16 f16;
using f16x8 = __attribute__((ext_vector_type(8))) _Float16;
using f32x4 = __attribute__((ext_vector_type(4))) float;

#define BATCH 2
#define SEQ   2048
#define DMODEL 4096
#define NH    32
#define NKV   8
#define HD    128
#define MTOK  (BATCH*SEQ)

// ---------------- f32 -> f16 convert (vectorized, 8 elems/thread) ----------------
__global__ __launch_bounds__(256) void cvt_f32_f16_k(const float* __restrict__ in,
                                                     f16* __restrict__ out, int n8) {
  int i = blockIdx.x * 256 + threadIdx.x;
  if (i >= n8) return;
  const float4* p = reinterpret_cast<const float4*>(in) + (size_t)i * 2;
  float4 a = p[0], b = p[1];
  f16x8 o = { (f16)a.x, (f16)a.y, (f16)a.z, (f16)a.w,
              (f16)b.x, (f16)b.y, (f16)b.z, (f16)b.w };
  reinterpret_cast<f16x8*>(out)[i] = o;
}

// ------------- w[K][N] f32 -> wT[N][K] f16, 32x32 LDS tile -------------
__global__ __launch_bounds__(256) void transpose_cvt_k(const float* __restrict__ w,
                                                       f16* __restrict__ wt, int Kd, int Nd) {
  __shared__ float tile[32][33];
  const int t = threadIdx.x;
  const int n0 = blockIdx.x * 32, k0 = blockIdx.y * 32;
  const int r = t >> 3, c4 = (t & 7) << 2;
  const float4 v = *reinterpret_cast<const float4*>(w + (size_t)(k0 + r) * Nd + n0 + c4);
  tile[r][c4 + 0] = v.x; tile[r][c4 + 1] = v.y; tile[r][c4 + 2] = v.z; tile[r][c4 + 3] = v.w;
  __syncthreads();
  union { f16 h[4]; ushort4 u4; } pk;
  pk.h[0] = (f16)tile[c4 + 0][r];
  pk.h[1] = (f16)tile[c4 + 1][r];
  pk.h[2] = (f16)tile[c4 + 2][r];
  pk.h[3] = (f16)tile[c4 + 3][r];
  *reinterpret_cast<ushort4*>(wt + (size_t)(n0 + r) * Kd + k0 + c4) = pk.u4;
}

// ------------- GEMM: C[m][n] = sum_k A[m][k] * BT[n][k]  (f16 in, MFMA 16x16x32) -------------
// MODE 0: store f16 row-major [M][N]
// MODE 1: store f16 V-transposed: [B][NKV][HD][SEQ]  (n -> kvh,d ; m -> b,s)
// MODE 2: store f32 row-major [M][N]
template<int MODE>
__global__ __launch_bounds__(256) void gemm_bt_k(const f16* __restrict__ A,
                                                 const f16* __restrict__ BT,
                                                 void* __restrict__ Cv,
                                                 int M, int N, int K) {
  __shared__ f16 Alds[128 * 64];   // 16 KB, XOR-swizzled 16B slots within 128B rows
  __shared__ f16 Blds[128 * 64];   // 16 KB
  const int t = threadIdx.x, lane = t & 63, w = t >> 6;
  const int nbn = N >> 7;
  const int nwg = gridDim.x;
  const int cpx = nwg >> 3;                      // grids here are multiples of 8
  const int bid = blockIdx.x;
  const int swz = (bid & 7) * cpx + (bid >> 3);  // XCD-aware swizzle (bijective: nwg%8==0)
  const int bm = swz / nbn, bn = swz % nbn;
  const size_t m0 = (size_t)bm << 7, n0 = (size_t)bn << 7;

  const int srow = t >> 3;        // 0..31 (staging row within pass)
  const int sslot = t & 7;        // 16B slot within 128B row
  char* ldsAw = (char*)Alds + w * 1024;
  char* ldsBw = (char*)Blds + w * 1024;

  f32x4 acc[4][4];
#pragma unroll
  for (int i = 0; i < 4; i++)
#pragma unroll
    for (int j = 0; j < 4; j++) acc[i][j] = f32x4{0.f, 0.f, 0.f, 0.f};

  const int wr = (w >> 1) << 6, wc = (w & 1) << 6;
  const int ll = lane & 15, lg = lane >> 4;

  for (int kt = 0; kt < K; kt += 64) {
    __syncthreads();  // WAR: all waves done reading previous tile
#pragma unroll
    for (int p = 0; p < 4; p++) {
      const int row = srow + (p << 5);
      // pre-swizzled SOURCE so linear-dest global_load_lds lands data at swizzled slot
      const int ssrc = (sslot ^ (row & 7)) << 3;
      const f16* gA = A + (m0 + row) * (size_t)K + kt + ssrc;
      __builtin_amdgcn_global_load_lds((const __attribute__((address_space(1))) void*)gA,
          (__attribute__((address_space(3))) void*)(ldsAw + p * 4096), 16, 0, 0);
      const f16* gB = BT + (n0 + row) * (size_t)K + kt + ssrc;
      __builtin_amdgcn_global_load_lds((const __attribute__((address_space(1))) void*)gB,
          (__attribute__((address_space(3))) void*)(ldsBw + p * 4096), 16, 0, 0);
    }
    __syncthreads();  // compiler drains vmcnt before barrier
#pragma unroll
    for (int kk = 0; kk < 2; kk++) {
      f16x8 af[4], bfr[4];
      const int slot = (kk << 2) + lg;
#pragma unroll
      for (int i = 0; i < 4; i++) {
        const int r = wr + (i << 4) + ll;
        af[i] = *reinterpret_cast<const f16x8*>((const char*)Alds + r * 128 + ((slot ^ (r & 7)) << 4));
      }
#pragma unroll
      for (int j = 0; j < 4; j++) {
        const int r = wc + (j << 4) + ll;
        bfr[j] = *reinterpret_cast<const f16x8*>((const char*)Blds + r * 128 + ((slot ^ (r & 7)) << 4));
      }
#pragma unroll
      for (int i = 0; i < 4; i++)
#pragma unroll
        for (int j = 0; j < 4; j++)
          acc[i][j] = __builtin_amdgcn_mfma_f32_16x16x32_f16(af[i], bfr[j], acc[i][j], 0, 0, 0);
    }
  }

  // epilogue: C layout col = lane&15, row = (lane>>4)*4 + reg
#pragma unroll
  for (int i = 0; i < 4; i++) {
    const size_t mrow = m0 + wr + (i << 4) + (lg << 2);
#pragma unroll
    for (int j = 0; j < 4; j++) {
      const size_t ncol = n0 + wc + (j << 4) + ll;
      if (MODE == 0) {
        f16* C = (f16*)Cv;
#pragma unroll
        for (int r = 0; r < 4; r++) C[(mrow + r) * N + ncol] = (f16)acc[i][j][r];
      } else if (MODE == 1) {
        f16* C = (f16*)Cv;
        const int kvh = (int)(ncol >> 7), d = (int)(ncol & 127);
        const int b = (int)(mrow >> 11), s = (int)(mrow & 2047);
        union { f16 h[4]; ushort4 u4; } pk;
#pragma unroll
        for (int r = 0; r < 4; r++) pk.h[r] = (f16)acc[i][j][r];
        *reinterpret_cast<ushort4*>(C + (((size_t)(b * NKV + kvh) * HD + d) * SEQ + s)) = pk.u4;
      } else {
        float* C = (float*)Cv;
#pragma unroll
        for (int r = 0; r < 4; r++) C[(mrow + r) * N + ncol] = acc[i][j][r];
      }
    }
  }
}

// ------------- flash attention: 1 wave/block, 16 q-rows, KBLK=64, non-causal GQA -------------
// Q,K: [B,S,NH/NKV,HD] f16 ; VT: [B,NKV,HD,S] f16 ; ctx out: [B,S,NH,HD] f16
__global__ __launch_bounds__(64) void attn_k(const f16* __restrict__ Q,
                                             const f16* __restrict__ Kb,
                                             const f16* __restrict__ VT,
                                             f16* __restrict__ ctx) {
  __shared__ f16 P_lds[16 * 72];  // [16 q][64 kv] padded to 72 (144B rows, 16B-aligned)
  const int lane = threadIdx.x;
  const int bid = blockIdx.x;
  const int qt = bid & 127, h = (bid >> 7) & 31, b = bid >> 12;
  const int kvh = h >> 2;          // N_REP = 4
  const int q0 = qt << 4;
  const int ll = lane & 15, lg = lane >> 4;

  const f16* Qb = Q + ((size_t)(b * SEQ + q0) * NH + h) * HD;
  const f16* Kh = Kb + ((size_t)b * SEQ * NKV + kvh) * HD;
  const f16* Vh = VT + ((size_t)(b * NKV + kvh)) * HD * SEQ;

  // Q A-fragments: row = lane&15, k(d) = kd*32 + lg*8 + j
  f16x8 qf[4];
#pragma unroll
  for (int kd = 0; kd < 4; kd++)
    qf[kd] = *reinterpret_cast<const f16x8*>(Qb + (size_t)ll * (NH * HD) + kd * 32 + lg * 8);

  float m_[4] = {-INFINITY, -INFINITY, -INFINITY, -INFINITY};
  float l_[4] = {0.f, 0.f, 0.f, 0.f};
  f32x4 o[8];
#pragma unroll
  for (int df = 0; df < 8; df++) o[df] = f32x4{0.f, 0.f, 0.f, 0.f};

  const float ksc = 0.08838834764831845f * 1.4426950408889634f;  // 1/sqrt(128) * log2(e)

  for (int kt = 0; kt < SEQ; kt += 64) {
    // S = Q @ K^T : B-frag col = kv (lane&15), k(d) contiguous from K rows
    f32x4 s[4];
#pragma unroll
    for (int nf = 0; nf < 4; nf++) {
      f32x4 a = f32x4{0.f, 0.f, 0.f, 0.f};
#pragma unroll
      for (int kd = 0; kd < 4; kd++) {
        f16x8 kf = *reinterpret_cast<const f16x8*>(
            Kh + (size_t)(kt + nf * 16 + ll) * (NKV * HD) + kd * 32 + lg * 8);
        a = __builtin_amdgcn_mfma_f32_16x16x32_f16(qf[kd], kf, a, 0, 0, 0);
      }
      s[nf] = a;
    }
    // online softmax; lane owns rows q = lg*4 + r, cols = lane&15 within 16-group
    float mx[4];
#pragma unroll
    for (int r = 0; r < 4; r++) {
#pragma unroll
      for (int nf = 0; nf < 4; nf++) s[nf][r] *= ksc;
      mx[r] = fmaxf(fmaxf(s[0][r], s[1][r]), fmaxf(s[2][r], s[3][r]));
#pragma unroll
      for (int off = 1; off < 16; off <<= 1) mx[r] = fmaxf(mx[r], __shfl_xor(mx[r], off, 64));
    }
    float corr[4];
#pragma unroll
    for (int r = 0; r < 4; r++) {
      const float mn = fmaxf(m_[r], mx[r]);
      corr[r] = __builtin_amdgcn_exp2f(m_[r] - mn);
      m_[r] = mn;
      float rs = 0.f;
#pragma unroll
      for (int nf = 0; nf < 4; nf++) {
        float p = __builtin_amdgcn_exp2f(s[nf][r] - mn);
        s[nf][r] = p;
        rs += p;
      }
#pragma unroll
      for (int off = 1; off < 16; off <<= 1) rs += __shfl_xor(rs, off, 64);
      l_[r] = l_[r] * corr[r] + rs;
    }
#pragma unroll
    for (int df = 0; df < 8; df++)
#pragma unroll
      for (int r = 0; r < 4; r++) o[df][r] *= corr[r];

    // P: C-layout -> A-layout via LDS roundtrip
    __syncthreads();
#pragma unroll
    for (int nf = 0; nf < 4; nf++)
#pragma unroll
      for (int r = 0; r < 4; r++)
        P_lds[(lg * 4 + r) * 72 + nf * 16 + ll] = (f16)s[nf][r];
    __syncthreads();

    f16x8 pf[2];
#pragma unroll
    for (int kf = 0; kf < 2; kf++)
      pf[kf] = *reinterpret_cast<const f16x8*>((const char*)P_lds + ll * 144 + kf * 64 + lg * 16);

    // O += P @ V : B-frag col = d (lane&15), k(kv) contiguous from VT rows
#pragma unroll
    for (int kf = 0; kf < 2; kf++)
#pragma unroll
      for (int df = 0; df < 8; df++) {
        f16x8 vf = *reinterpret_cast<const f16x8*>(
            Vh + (size_t)(df * 16 + ll) * SEQ + kt + kf * 32 + lg * 8);
        o[df] = __builtin_amdgcn_mfma_f32_16x16x32_f16(pf[kf], vf, o[df], 0, 0, 0);
      }
  }

  float inv[4];
#pragma unroll
  for (int r = 0; r < 4; r++) inv[r] = 1.0f / l_[r];
  f16* cb = ctx + ((size_t)(b * SEQ + q0) * NH + h) * HD;
#pragma unroll
  for (int df = 0; df < 8; df++)
#pragma unroll
    for (int r = 0; r < 4; r++)
      cb[(size_t)(lg * 4 + r) * (NH * HD) + df * 16 + ll] = (f16)(o[df][r] * inv[r]);
}

extern "C" void kernel_launch(void* const* d_in, const int* in_sizes, int n_in,
                              void* d_out, int out_size, void* d_ws, size_t ws_size,
                              hipStream_t stream) {
  (void)in_sizes; (void)n_in; (void)out_size;
  const float* x  = (const float*)d_in[0];
  const float* wq = (const float*)d_in[1];
  const float* wk = (const float*)d_in[2];
  const float* wv = (const float*)d_in[3];
  const float* wo = (const float*)d_in[4];
  float* out = (float*)d_out;

  const size_t SZ_X  = (size_t)MTOK * DMODEL * sizeof(f16);      // 33,554,432
  const size_t SZ_KV = (size_t)MTOK * NKV * HD * sizeof(f16);    //  8,388,608
  if (ws_size < 3 * SZ_X + 2 * SZ_KV) return;  // need ~117.4 MB scratch

  char* ws = (char*)d_ws;
  f16* xh  = (f16*)ws;                      // x in f16; reused as ctx after GEMM3
  f16* wT  = (f16*)(ws + SZ_X);             // transposed weight (reused per GEMM)
  f16* Qb  = (f16*)(ws + 2 * SZ_X);         // [B,S,NH,HD]
  f16* Kb  = (f16*)(ws + 3 * SZ_X);         // [B,S,NKV,HD]
  f16* VTb = (f16*)(ws + 3 * SZ_X + SZ_KV); // [B,NKV,HD,S]

  cvt_f32_f16_k<<<dim3(MTOK * DMODEL / 8 / 256), 256, 0, stream>>>(x, xh, MTOK * DMODEL / 8);

  transpose_cvt_k<<<dim3(DMODEL / 32, DMODEL / 32), 256, 0, stream>>>(wq, wT, DMODEL, DMODEL);
  gemm_bt_k<0><<<dim3((MTOK / 128) * (DMODEL / 128)), 256, 0, stream>>>(xh, wT, Qb, MTOK, DMODEL, DMODEL);

  transpose_cvt_k<<<dim3(NKV * HD / 32, DMODEL / 32), 256, 0, stream>>>(wk, wT, DMODEL, NKV * HD);
  gemm_bt_k<0><<<dim3((MTOK / 128) * ((NKV * HD) / 128)), 256, 0, stream>>>(xh, wT, Kb, MTOK, NKV * HD, DMODEL);

  transpose_cvt_k<<<dim3(NKV * HD / 32, DMODEL / 32), 256, 0, stream>>>(wv, wT, DMODEL, NKV * HD);
  gemm_bt_k<1><<<dim3((MTOK / 128) * ((NKV * HD) / 128)), 256, 0, stream>>>(xh, wT, VTb, MTOK, NKV * HD, DMODEL);

  attn_k<<<dim3(BATCH * NH * (SEQ / 16)), 64, 0, stream>>>(Qb, Kb, VTb, xh);

  transpose_cvt_k<<<dim3(DMODEL / 32, DMODEL / 32), 256, 0, stream>>>(wo, wT, DMODEL, DMODEL);
  gemm_bt_k<2><<<dim3((MTOK / 128) * (DMODEL / 128)), 256, 0, stream>>>(xh, wT, out, MTOK, DMODEL, DMODEL);
}

// Round 2
// 853.781 us; speedup vs baseline: 1.7619x; 1.7619x over previous
//
#include <hip/hip_runtime.h>
#include <math.h>

typedef _Float16 f16;
using f16x8 = __attribute__((ext_vector_type(8))) _Float16;
using f32x4 = __attribute__((ext_vector_type(4))) float;

#define BATCH 2
#define SEQ   2048
#define DMODEL 4096
#define NH    32
#define NKV   8
#define HD    128
#define MTOK  (BATCH*SEQ)

// ---------------- f32 -> f16 convert (vectorized, 8 elems/thread) ----------------
__global__ __launch_bounds__(256) void cvt_f32_f16_k(const float* __restrict__ in,
                                                     f16* __restrict__ out, int n8) {
  int i = blockIdx.x * 256 + threadIdx.x;
  if (i >= n8) return;
  const float4* p = reinterpret_cast<const float4*>(in) + (size_t)i * 2;
  float4 a = p[0], b = p[1];
  f16x8 o = { (f16)a.x, (f16)a.y, (f16)a.z, (f16)a.w,
              (f16)b.x, (f16)b.y, (f16)b.z, (f16)b.w };
  reinterpret_cast<f16x8*>(out)[i] = o;
}

// ------------- w[K][N] f32 -> wT[N][K] f16, 32x32 LDS tile -------------
__global__ __launch_bounds__(256) void transpose_cvt_k(const float* __restrict__ w,
                                                       f16* __restrict__ wt, int Kd, int Nd) {
  __shared__ float tile[32][33];
  const int t = threadIdx.x;
  const int n0 = blockIdx.x * 32, k0 = blockIdx.y * 32;
  const int r = t >> 3, c4 = (t & 7) << 2;
  const float4 v = *reinterpret_cast<const float4*>(w + (size_t)(k0 + r) * Nd + n0 + c4);
  tile[r][c4 + 0] = v.x; tile[r][c4 + 1] = v.y; tile[r][c4 + 2] = v.z; tile[r][c4 + 3] = v.w;
  __syncthreads();
  union { f16 h[4]; ushort4 u4; } pk;
  pk.h[0] = (f16)tile[c4 + 0][r];
  pk.h[1] = (f16)tile[c4 + 1][r];
  pk.h[2] = (f16)tile[c4 + 2][r];
  pk.h[3] = (f16)tile[c4 + 3][r];
  *reinterpret_cast<ushort4*>(wt + (size_t)(n0 + r) * Kd + k0 + c4) = pk.u4;
}

// ------------- GEMM: C[m][n] = sum_k A[m][k] * BT[n][k]  (f16 in, MFMA 16x16x32) -------------
template<int MODE>
__global__ __launch_bounds__(256) void gemm_bt_k(const f16* __restrict__ A,
                                                 const f16* __restrict__ BT,
                                                 void* __restrict__ Cv,
                                                 int M, int N, int K) {
  __shared__ f16 Alds[128 * 64];
  __shared__ f16 Blds[128 * 64];
  const int t = threadIdx.x, lane = t & 63, w = t >> 6;
  const int nbn = N >> 7;
  const int nwg = gridDim.x;
  const int cpx = nwg >> 3;
  const int bid = blockIdx.x;
  const int swz = (bid & 7) * cpx + (bid >> 3);
  const int bm = swz / nbn, bn = swz % nbn;
  const size_t m0 = (size_t)bm << 7, n0 = (size_t)bn << 7;

  const int srow = t >> 3;
  const int sslot = t & 7;
  char* ldsAw = (char*)Alds + w * 1024;
  char* ldsBw = (char*)Blds + w * 1024;

  f32x4 acc[4][4];
#pragma unroll
  for (int i = 0; i < 4; i++)
#pragma unroll
    for (int j = 0; j < 4; j++) acc[i][j] = f32x4{0.f, 0.f, 0.f, 0.f};

  const int wr = (w >> 1) << 6, wc = (w & 1) << 6;
  const int ll = lane & 15, lg = lane >> 4;

  for (int kt = 0; kt < K; kt += 64) {
    __syncthreads();
#pragma unroll
    for (int p = 0; p < 4; p++) {
      const int row = srow + (p << 5);
      const int ssrc = (sslot ^ (row & 7)) << 3;
      const f16* gA = A + (m0 + row) * (size_t)K + kt + ssrc;
      __builtin_amdgcn_global_load_lds((const __attribute__((address_space(1))) void*)gA,
          (__attribute__((address_space(3))) void*)(ldsAw + p * 4096), 16, 0, 0);
      const f16* gB = BT + (n0 + row) * (size_t)K + kt + ssrc;
      __builtin_amdgcn_global_load_lds((const __attribute__((address_space(1))) void*)gB,
          (__attribute__((address_space(3))) void*)(ldsBw + p * 4096), 16, 0, 0);
    }
    __syncthreads();
#pragma unroll
    for (int kk = 0; kk < 2; kk++) {
      f16x8 af[4], bfr[4];
      const int slot = (kk << 2) + lg;
#pragma unroll
      for (int i = 0; i < 4; i++) {
        const int r = wr + (i << 4) + ll;
        af[i] = *reinterpret_cast<const f16x8*>((const char*)Alds + r * 128 + ((slot ^ (r & 7)) << 4));
      }
#pragma unroll
      for (int j = 0; j < 4; j++) {
        const int r = wc + (j << 4) + ll;
        bfr[j] = *reinterpret_cast<const f16x8*>((const char*)Blds + r * 128 + ((slot ^ (r & 7)) << 4));
      }
#pragma unroll
      for (int i = 0; i < 4; i++)
#pragma unroll
        for (int j = 0; j < 4; j++)
          acc[i][j] = __builtin_amdgcn_mfma_f32_16x16x32_f16(af[i], bfr[j], acc[i][j], 0, 0, 0);
    }
  }

#pragma unroll
  for (int i = 0; i < 4; i++) {
    const size_t mrow = m0 + wr + (i << 4) + (lg << 2);
#pragma unroll
    for (int j = 0; j < 4; j++) {
      const size_t ncol = n0 + wc + (j << 4) + ll;
      if (MODE == 0) {
        f16* C = (f16*)Cv;
#pragma unroll
        for (int r = 0; r < 4; r++) C[(mrow + r) * N + ncol] = (f16)acc[i][j][r];
      } else if (MODE == 1) {
        f16* C = (f16*)Cv;
        const int kvh = (int)(ncol >> 7), d = (int)(ncol & 127);
        const int b = (int)(mrow >> 11), s = (int)(mrow & 2047);
        union { f16 h[4]; ushort4 u4; } pk;
#pragma unroll
        for (int r = 0; r < 4; r++) pk.h[r] = (f16)acc[i][j][r];
        *reinterpret_cast<ushort4*>(C + (((size_t)(b * NKV + kvh) * HD + d) * SEQ + s)) = pk.u4;
      } else {
        float* C = (float*)Cv;
#pragma unroll
        for (int r = 0; r < 4; r++) C[(mrow + r) * N + ncol] = acc[i][j][r];
      }
    }
  }
}

// ------------- flash attention v2: 4 waves/block = 4 GQA heads sharing one kv head -------------
// K tile [64 kv][128 d] and VT tile [128 d][64 kv] staged in LDS (double-buffered,
// XOR-swizzled 16B slots), shared by all 4 waves. Each wave: 16 q-rows of its head.
// Q,K: [B,S,{NH|NKV},HD] f16 ; VT: [B,NKV,HD,S] f16 ; ctx out: [B,S,NH,HD] f16
__global__ __launch_bounds__(256) void attn_k2(const f16* __restrict__ Q,
                                               const f16* __restrict__ Kb,
                                               const f16* __restrict__ VT,
                                               f16* __restrict__ ctx) {
  __shared__ f16 Klds[2][64 * 128];   // 16 KB x2: 64 kv-rows of 256B (16 slots)
  __shared__ f16 Vlds[2][128 * 64];   // 16 KB x2: 128 d-rows of 128B (8 slots)
  __shared__ f16 Plds[4][16 * 72];    // per-wave P roundtrip (2.3 KB each)

  const int t = threadIdx.x, lane = t & 63, w = t >> 6;
  const int bid = blockIdx.x;
  // XCD-bijective swizzle: grid=2048, 256 consecutive work-ids (= 2 full (b,kvh)
  // K/V sets = 2 MB) per XCD -> staging re-reads stay in that XCD's 4 MB L2.
  const int swz = (bid & 7) * 256 + (bid >> 3);
  const int qt = swz & 127, kvh = (swz >> 7) & 7, b = swz >> 10;
  const int h = kvh * 4 + w;          // this wave's query head
  const int q0 = qt << 4;
  const int ll = lane & 15, lg = lane >> 4;

  const f16* Qb = Q + ((size_t)(b * SEQ + q0) * NH + h) * HD;
  const f16* Kh = Kb + ((size_t)b * SEQ * NKV + kvh) * HD;     // token stride NKV*HD
  const f16* Vh = VT + ((size_t)(b * NKV + kvh)) * HD * SEQ;   // d stride SEQ

  // Q A-fragments: row = lane&15, k(d) = kd*32 + lg*8 + j
  f16x8 qf[4];
#pragma unroll
  for (int kd = 0; kd < 4; kd++)
    qf[kd] = *reinterpret_cast<const f16x8*>(Qb + (size_t)ll * (NH * HD) + kd * 32 + lg * 8);

  float m_[4] = {-INFINITY, -INFINITY, -INFINITY, -INFINITY};
  float l_[4] = {0.f, 0.f, 0.f, 0.f};
  f32x4 o[8];
#pragma unroll
  for (int df = 0; df < 8; df++) o[df] = f32x4{0.f, 0.f, 0.f, 0.f};

  const float ksc = 0.08838834764831845f * 1.4426950408889634f;  // 1/sqrt(128)*log2(e)

  const int lr4 = lane >> 4;   // K staging: row-in-4
  const int ls16 = lane & 15;  // K staging: linear slot
  const int lr8 = lane >> 3;   // V staging: row-in-8
  const int ls8 = lane & 7;    // V staging: linear slot

  // stage K[64][128] + VT[128][64] tile kt into buffer bufi.
  // linear LDS dest + inverse-swizzled global source (rule #21).
  auto stage = [&](int bufi, int kt) {
#pragma unroll
    for (int c = 0; c < 4; c++) {
      const int row = w * 16 + c * 4 + lr4;
      const int slot = ls16 ^ (row & 7);
      const f16* src = Kh + (size_t)(kt + row) * (NKV * HD) + slot * 8;
      __builtin_amdgcn_global_load_lds((const __attribute__((address_space(1))) void*)src,
          (__attribute__((address_space(3))) void*)(&Klds[bufi][(w * 16 + c * 4) * 128]), 16, 0, 0);
    }
#pragma unroll
    for (int c = 0; c < 4; c++) {
      const int row = w * 32 + c * 8 + lr8;
      const int slot = ls8 ^ (row & 7);
      const f16* src = Vh + (size_t)row * SEQ + kt + slot * 8;
      __builtin_amdgcn_global_load_lds((const __attribute__((address_space(1))) void*)src,
          (__attribute__((address_space(3))) void*)(&Vlds[bufi][(w * 32 + c * 8) * 64]), 16, 0, 0);
    }
  };

  stage(0, 0);
  __syncthreads();  // drains vmcnt before barrier: buffer 0 ready

  for (int kt = 0; kt < SEQ; kt += 64) {
    const int buf = (kt >> 6) & 1;
    if (kt + 64 < SEQ) stage(buf ^ 1, kt + 64);  // prefetch next tile (T3 2-phase)

    const char* Kt = (const char*)Klds[buf];
    const char* Vt = (const char*)Vlds[buf];

    // S = Q @ K^T : B-frag col = kv (ll), k = d; K row = nf*16+ll, slot kd*4+lg (swizzled)
    f32x4 s[4];
#pragma unroll
    for (int nf = 0; nf < 4; nf++) {
      f32x4 a = f32x4{0.f, 0.f, 0.f, 0.f};
#pragma unroll
      for (int kd = 0; kd < 4; kd++) {
        const int row = nf * 16 + ll;
        f16x8 kf = *reinterpret_cast<const f16x8*>(
            Kt + row * 256 + ((((kd << 2) + lg) ^ (row & 7)) << 4));
        a = __builtin_amdgcn_mfma_f32_16x16x32_f16(qf[kd], kf, a, 0, 0, 0);
      }
      s[nf] = a;
    }

    // online softmax; lane owns rows q = lg*4 + r, col group = ll
    float mx[4];
#pragma unroll
    for (int r = 0; r < 4; r++) {
#pragma unroll
      for (int nf = 0; nf < 4; nf++) s[nf][r] *= ksc;
      mx[r] = fmaxf(fmaxf(s[0][r], s[1][r]), fmaxf(s[2][r], s[3][r]));
#pragma unroll
      for (int off = 1; off < 16; off <<= 1) mx[r] = fmaxf(mx[r], __shfl_xor(mx[r], off, 64));
    }
    float corr[4];
#pragma unroll
    for (int r = 0; r < 4; r++) {
      const float mn = fmaxf(m_[r], mx[r]);
      corr[r] = __builtin_amdgcn_exp2f(m_[r] - mn);
      m_[r] = mn;
      float rs = 0.f;
#pragma unroll
      for (int nf = 0; nf < 4; nf++) {
        float p = __builtin_amdgcn_exp2f(s[nf][r] - mn);
        s[nf][r] = p;
        rs += p;
      }
#pragma unroll
      for (int off = 1; off < 16; off <<= 1) rs += __shfl_xor(rs, off, 64);
      l_[r] = l_[r] * corr[r] + rs;
    }
#pragma unroll
    for (int df = 0; df < 8; df++)
#pragma unroll
      for (int r = 0; r < 4; r++) o[df][r] *= corr[r];

    // P: C-layout -> A-layout via per-wave-private LDS (same-wave ds order: no barrier)
#pragma unroll
    for (int nf = 0; nf < 4; nf++)
#pragma unroll
      for (int r = 0; r < 4; r++)
        Plds[w][(lg * 4 + r) * 72 + nf * 16 + ll] = (f16)s[nf][r];

    f16x8 pf[2];
#pragma unroll
    for (int kf = 0; kf < 2; kf++)
      pf[kf] = *reinterpret_cast<const f16x8*>((const char*)Plds[w] + ll * 144 + kf * 64 + lg * 16);

    // O += P @ V : B-frag col = d (ll), k = kv; VT row = df*16+ll, slot kf*4+lg (swizzled)
#pragma unroll
    for (int kf = 0; kf < 2; kf++)
#pragma unroll
      for (int df = 0; df < 8; df++) {
        const int row = df * 16 + ll;
        f16x8 vf = *reinterpret_cast<const f16x8*>(
            Vt + row * 128 + ((((kf << 2) + lg) ^ (row & 7)) << 4));
        o[df] = __builtin_amdgcn_mfma_f32_16x16x32_f16(pf[kf], vf, o[df], 0, 0, 0);
      }

    __syncthreads();  // drains vmcnt (next tile staged) + all waves done with buf
  }

  float inv[4];
#pragma unroll
  for (int r = 0; r < 4; r++) inv[r] = 1.0f / l_[r];
  f16* cb = ctx + ((size_t)(b * SEQ + q0) * NH + h) * HD;
#pragma unroll
  for (int df = 0; df < 8; df++)
#pragma unroll
    for (int r = 0; r < 4; r++)
      cb[(size_t)(lg * 4 + r) * (NH * HD) + df * 16 + ll] = (f16)(o[df][r] * inv[r]);
}

extern "C" void kernel_launch(void* const* d_in, const int* in_sizes, int n_in,
                              void* d_out, int out_size, void* d_ws, size_t ws_size,
                              hipStream_t stream) {
  (void)in_sizes; (void)n_in; (void)out_size;
  const float* x  = (const float*)d_in[0];
  const float* wq = (const float*)d_in[1];
  const float* wk = (const float*)d_in[2];
  const float* wv = (const float*)d_in[3];
  const float* wo = (const float*)d_in[4];
  float* out = (float*)d_out;

  const size_t SZ_X  = (size_t)MTOK * DMODEL * sizeof(f16);
  const size_t SZ_KV = (size_t)MTOK * NKV * HD * sizeof(f16);
  if (ws_size < 3 * SZ_X + 2 * SZ_KV) return;

  char* ws = (char*)d_ws;
  f16* xh  = (f16*)ws;
  f16* wT  = (f16*)(ws + SZ_X);
  f16* Qb  = (f16*)(ws + 2 * SZ_X);
  f16* Kb  = (f16*)(ws + 3 * SZ_X);
  f16* VTb = (f16*)(ws + 3 * SZ_X + SZ_KV);

  cvt_f32_f16_k<<<dim3(MTOK * DMODEL / 8 / 256), 256, 0, stream>>>(x, xh, MTOK * DMODEL / 8);

  transpose_cvt_k<<<dim3(DMODEL / 32, DMODEL / 32), 256, 0, stream>>>(wq, wT, DMODEL, DMODEL);
  gemm_bt_k<0><<<dim3((MTOK / 128) * (DMODEL / 128)), 256, 0, stream>>>(xh, wT, Qb, MTOK, DMODEL, DMODEL);

  transpose_cvt_k<<<dim3(NKV * HD / 32, DMODEL / 32), 256, 0, stream>>>(wk, wT, DMODEL, NKV * HD);
  gemm_bt_k<0><<<dim3((MTOK / 128) * ((NKV * HD) / 128)), 256, 0, stream>>>(xh, wT, Kb, MTOK, NKV * HD, DMODEL);

  transpose_cvt_k<<<dim3(NKV * HD / 32, DMODEL / 32), 256, 0, stream>>>(wv, wT, DMODEL, NKV * HD);
  gemm_bt_k<1><<<dim3((MTOK / 128) * ((NKV * HD) / 128)), 256, 0, stream>>>(xh, wT, VTb, MTOK, NKV * HD, DMODEL);

  attn_k2<<<dim3(BATCH * NKV * (SEQ / 16)), 256, 0, stream>>>(Qb, Kb, VTb, xh);

  transpose_cvt_k<<<dim3(DMODEL / 32, DMODEL / 32), 256, 0, stream>>>(wo, wT, DMODEL, DMODEL);
  gemm_bt_k<2><<<dim3((MTOK / 128) * (DMODEL / 128)), 256, 0, stream>>>(xh, wT, out, MTOK, DMODEL, DMODEL);
}

// Round 3
// 656.082 us; speedup vs baseline: 2.2929x; 1.3013x over previous
//
#include <hip/hip_runtime.h>
#include <math.h>

typedef _Float16 f16;
using f16x8 = __attribute__((ext_vector_type(8))) _Float16;
using f32x4 = __attribute__((ext_vector_type(4))) float;

#define BATCH 2
#define SEQ   2048
#define DMODEL 4096
#define NH    32
#define NKV   8
#define HD    128
#define MTOK  (BATCH*SEQ)

// ---------------- f32 -> f16 convert ----------------
__global__ __launch_bounds__(256) void cvt_f32_f16_k(const float* __restrict__ in,
                                                     f16* __restrict__ out, int n8) {
  int i = blockIdx.x * 256 + threadIdx.x;
  if (i >= n8) return;
  const float4* p = reinterpret_cast<const float4*>(in) + (size_t)i * 2;
  float4 a = p[0], b = p[1];
  f16x8 o = { (f16)a.x, (f16)a.y, (f16)a.z, (f16)a.w,
              (f16)b.x, (f16)b.y, (f16)b.z, (f16)b.w };
  reinterpret_cast<f16x8*>(out)[i] = o;
}

// ------------- w[K][N] f32 -> wT[N][K] f16 -------------
__global__ __launch_bounds__(256) void transpose_cvt_k(const float* __restrict__ w,
                                                       f16* __restrict__ wt, int Kd, int Nd) {
  __shared__ float tile[32][33];
  const int t = threadIdx.x;
  const int n0 = blockIdx.x * 32, k0 = blockIdx.y * 32;
  const int r = t >> 3, c4 = (t & 7) << 2;
  const float4 v = *reinterpret_cast<const float4*>(w + (size_t)(k0 + r) * Nd + n0 + c4);
  tile[r][c4 + 0] = v.x; tile[r][c4 + 1] = v.y; tile[r][c4 + 2] = v.z; tile[r][c4 + 3] = v.w;
  __syncthreads();
  union { f16 h[4]; ushort4 u4; } pk;
  pk.h[0] = (f16)tile[c4 + 0][r];
  pk.h[1] = (f16)tile[c4 + 1][r];
  pk.h[2] = (f16)tile[c4 + 2][r];
  pk.h[3] = (f16)tile[c4 + 3][r];
  *reinterpret_cast<ushort4*>(wt + (size_t)(n0 + r) * Kd + k0 + c4) = pk.u4;
}

// ------------- 128^2 GEMM (kept for K/V projections, N=1024) -------------
template<int MODE>
__global__ __launch_bounds__(256) void gemm_bt_k(const f16* __restrict__ A,
                                                 const f16* __restrict__ BT,
                                                 void* __restrict__ Cv,
                                                 int M, int N, int K) {
  __shared__ f16 Alds[128 * 64];
  __shared__ f16 Blds[128 * 64];
  const int t = threadIdx.x, lane = t & 63, w = t >> 6;
  const int nbn = N >> 7;
  const int nwg = gridDim.x;
  const int cpx = nwg >> 3;
  const int bid = blockIdx.x;
  const int swz = (bid & 7) * cpx + (bid >> 3);
  const int bm = swz / nbn, bn = swz % nbn;
  const size_t m0 = (size_t)bm << 7, n0 = (size_t)bn << 7;

  const int srow = t >> 3;
  const int sslot = t & 7;
  char* ldsAw = (char*)Alds + w * 1024;
  char* ldsBw = (char*)Blds + w * 1024;

  f32x4 acc[4][4];
#pragma unroll
  for (int i = 0; i < 4; i++)
#pragma unroll
    for (int j = 0; j < 4; j++) acc[i][j] = f32x4{0.f, 0.f, 0.f, 0.f};

  const int wr = (w >> 1) << 6, wc = (w & 1) << 6;
  const int ll = lane & 15, lg = lane >> 4;

  for (int kt = 0; kt < K; kt += 64) {
    __syncthreads();
#pragma unroll
    for (int p = 0; p < 4; p++) {
      const int row = srow + (p << 5);
      const int ssrc = (sslot ^ (row & 7)) << 3;
      const f16* gA = A + (m0 + row) * (size_t)K + kt + ssrc;
      __builtin_amdgcn_global_load_lds((const __attribute__((address_space(1))) void*)gA,
          (__attribute__((address_space(3))) void*)(ldsAw + p * 4096), 16, 0, 0);
      const f16* gB = BT + (n0 + row) * (size_t)K + kt + ssrc;
      __builtin_amdgcn_global_load_lds((const __attribute__((address_space(1))) void*)gB,
          (__attribute__((address_space(3))) void*)(ldsBw + p * 4096), 16, 0, 0);
    }
    __syncthreads();
#pragma unroll
    for (int kk = 0; kk < 2; kk++) {
      f16x8 af[4], bfr[4];
      const int slot = (kk << 2) + lg;
#pragma unroll
      for (int i = 0; i < 4; i++) {
        const int r = wr + (i << 4) + ll;
        af[i] = *reinterpret_cast<const f16x8*>((const char*)Alds + r * 128 + ((slot ^ (r & 7)) << 4));
      }
#pragma unroll
      for (int j = 0; j < 4; j++) {
        const int r = wc + (j << 4) + ll;
        bfr[j] = *reinterpret_cast<const f16x8*>((const char*)Blds + r * 128 + ((slot ^ (r & 7)) << 4));
      }
#pragma unroll
      for (int i = 0; i < 4; i++)
#pragma unroll
        for (int j = 0; j < 4; j++)
          acc[i][j] = __builtin_amdgcn_mfma_f32_16x16x32_f16(af[i], bfr[j], acc[i][j], 0, 0, 0);
    }
  }

#pragma unroll
  for (int i = 0; i < 4; i++) {
    const size_t mrow = m0 + wr + (i << 4) + (lg << 2);
#pragma unroll
    for (int j = 0; j < 4; j++) {
      const size_t ncol = n0 + wc + (j << 4) + ll;
      if (MODE == 0) {
        f16* C = (f16*)Cv;
#pragma unroll
        for (int r = 0; r < 4; r++) C[(mrow + r) * N + ncol] = (f16)acc[i][j][r];
      } else if (MODE == 1) {
        f16* C = (f16*)Cv;
        const int kvh = (int)(ncol >> 7), d = (int)(ncol & 127);
        const int b = (int)(mrow >> 11), s = (int)(mrow & 2047);
        union { f16 h[4]; ushort4 u4; } pk;
#pragma unroll
        for (int r = 0; r < 4; r++) pk.h[r] = (f16)acc[i][j][r];
        *reinterpret_cast<ushort4*>(C + (((size_t)(b * NKV + kvh) * HD + d) * SEQ + s)) = pk.u4;
      } else {
        float* C = (float*)Cv;
#pragma unroll
        for (int r = 0; r < 4; r++) C[(mrow + r) * N + ncol] = acc[i][j][r];
      }
    }
  }
}

// ------------- 256^2 8-phase GEMM (T2+T3+T4+T5) for the two 4096^3 GEMMs -------------
// BM=BN=256, BK=64, 512 thr = 8 waves (2M x 4N), per-wave C = 128x64 (interleaved 16-row frags).
// LDS 128 KB: 2 dbuf x 4 units (A0,A1,B0,B1) x 16 KB. Counted vmcnt(6) at phases 4/8 only.
// MODE 0: f16 row-major out; MODE 2: f32 row-major out.
template<int MODE>
__global__ __launch_bounds__(512, 2) void gemm256_k(const f16* __restrict__ A,
                                                    const f16* __restrict__ BT,
                                                    void* __restrict__ Cv,
                                                    int M, int N, int K) {
  __shared__ f16 lds[2 * 4 * 128 * 64];   // 128 KB
  char* ldsb = (char*)lds;

  const int t = threadIdx.x, lane = t & 63, w = t >> 6;
  const int wm = w >> 2, wn = w & 3;
  const int ll = lane & 15, lg = lane >> 4;
  const int nbn = N >> 8;
  const int nwg = gridDim.x, cpx = nwg >> 3, bid = blockIdx.x;
  const int swz = (bid & 7) * cpx + (bid >> 3);
  const int bm = swz / nbn, bn = swz % nbn;
  const size_t m0 = (size_t)bm << 8, n0 = (size_t)bn << 8;
  const int NT = K >> 6;

  // stage one 16 KB unit (128 rows x 64 k, f16) of tile at k-offset ktS into lds[buf][unit].
  // unit: 0=A rows 0-127, 1=A rows 128-255, 2=B rows 0-127, 3=B rows 128-255.
  auto stage = [&](int bufI, int unit, int ktS) {
    const f16* base = (unit < 2) ? (A + (m0 + (size_t)(unit & 1) * 128) * (size_t)K)
                                 : (BT + (n0 + (size_t)(unit & 1) * 128) * (size_t)K);
#pragma unroll
    for (int rr = 0; rr < 2; rr++) {
      const int u = t + rr * 512;
      const int row = u >> 3, lin = u & 7;
      const int slot = lin ^ (row & 7);
      const f16* src = base + (size_t)row * K + ktS + slot * 8;
      char* dst = ldsb + (size_t)(bufI * 4 + unit) * 16384 + (size_t)(w * 64 + rr * 512) * 16;
      __builtin_amdgcn_global_load_lds((const __attribute__((address_space(1))) void*)src,
          (__attribute__((address_space(3))) void*)dst, 16, 0, 0);
    }
  };

  f32x4 acc[8][4];
#pragma unroll
  for (int i = 0; i < 8; i++)
#pragma unroll
    for (int j = 0; j < 4; j++) acc[i][j] = f32x4{0.f, 0.f, 0.f, 0.f};

  f16x8 af[4][2];        // current A M-half frags
  f16x8 bfr[2][2][2];    // [N-half][ni][kk]

  // prologue: tile0 all 4 units -> buf0; tile1 A0,B0,B1 -> buf1; wait tile0 landed.
  stage(0, 0, 0); stage(0, 2, 0); stage(0, 3, 0); stage(0, 1, 0);
  stage(1, 0, 64); stage(1, 2, 64); stage(1, 3, 64);
  asm volatile("s_waitcnt vmcnt(6)" ::: "memory");
  __builtin_amdgcn_sched_barrier(0);
  __builtin_amdgcn_s_barrier();

#define PH(RBUF, RDA, RDB, SBUF, SUNIT, STILE, VM, MH, NHQ) do {                          \
    if ((RDA) >= 0) {                                                                     \
      const char* ab = ldsb + (size_t)((RBUF) * 4 + (RDA)) * 16384;                       \
      _Pragma("unroll") for (int mi = 0; mi < 4; mi++)                                    \
        _Pragma("unroll") for (int kk = 0; kk < 2; kk++)                                  \
          af[mi][kk] = *reinterpret_cast<const f16x8*>(ab + (mi * 32 + wm * 16 + ll) * 128\
                               + ((((kk << 2) + lg) ^ (ll & 7)) << 4));                   \
    }                                                                                     \
    if ((RDB) >= 0) {                                                                     \
      const char* bb = ldsb + (size_t)((RBUF) * 4 + 2 + (RDB)) * 16384;                   \
      _Pragma("unroll") for (int ni = 0; ni < 2; ni++)                                    \
        _Pragma("unroll") for (int kk = 0; kk < 2; kk++)                                  \
          bfr[RDB][ni][kk] = *reinterpret_cast<const f16x8*>(bb +                         \
                               (wn * 32 + ni * 16 + ll) * 128                             \
                               + ((((kk << 2) + lg) ^ (ll & 7)) << 4));                   \
    }                                                                                     \
    stage((SBUF), (SUNIT), ((STILE) & (NT - 1)) << 6);                                    \
    if (VM) { asm volatile("s_waitcnt vmcnt(6)" ::: "memory");                            \
              __builtin_amdgcn_sched_barrier(0); }                                        \
    __builtin_amdgcn_s_barrier();                                                         \
    asm volatile("s_waitcnt lgkmcnt(0)" ::: "memory");                                    \
    __builtin_amdgcn_sched_barrier(0);                                                    \
    __builtin_amdgcn_s_setprio(1);                                                        \
    _Pragma("unroll") for (int kk = 0; kk < 2; kk++)                                      \
      _Pragma("unroll") for (int mi = 0; mi < 4; mi++)                                    \
        _Pragma("unroll") for (int ni = 0; ni < 2; ni++)                                  \
          acc[(MH) * 4 + mi][(NHQ) * 2 + ni] = __builtin_amdgcn_mfma_f32_16x16x32_f16(    \
              af[mi][kk], bfr[NHQ][ni][kk], acc[(MH) * 4 + mi][(NHQ) * 2 + ni], 0, 0, 0); \
    __builtin_amdgcn_s_setprio(0);                                                        \
    __builtin_amdgcn_s_barrier();                                                         \
  } while (0)

  for (int tt = 0; tt < NT; tt += 2) {
    PH(0,  0,  0, 1, 1, tt + 1, false, 0, 0);  // read buf0 A0+B0; stage buf1.A1 (tile tt+1)
    PH(0, -1,  1, 0, 0, tt + 2, false, 0, 1);  // read buf0 B1;    stage buf0.A0 (tile tt+2)
    PH(0,  1, -1, 0, 2, tt + 2, false, 1, 0);  // read buf0 A1;    stage buf0.B0
    PH(0, -1, -1, 0, 3, tt + 2, true , 1, 1);  //                  stage buf0.B1; vmcnt(6)
    PH(1,  0,  0, 0, 1, tt + 2, false, 0, 0);  // read buf1 A0+B0; stage buf0.A1
    PH(1, -1,  1, 1, 0, tt + 3, false, 0, 1);  // read buf1 B1;    stage buf1.A0 (tile tt+3)
    PH(1,  1, -1, 1, 2, tt + 3, false, 1, 0);  // read buf1 A1;    stage buf1.B0
    PH(1, -1, -1, 1, 3, tt + 3, true , 1, 1);  //                  stage buf1.B1; vmcnt(6)
  }
#undef PH

  // epilogue: C row = m0 + mh*128 + mi*32 + wm*16 + lg*4 + rr ; col = n0 + nh*128 + wn*32 + ni*16 + ll
#pragma unroll
  for (int mh = 0; mh < 2; mh++)
#pragma unroll
    for (int mi = 0; mi < 4; mi++) {
      const size_t r0 = m0 + mh * 128 + mi * 32 + wm * 16 + lg * 4;
#pragma unroll
      for (int nh = 0; nh < 2; nh++)
#pragma unroll
        for (int ni = 0; ni < 2; ni++) {
          const size_t c = n0 + nh * 128 + wn * 32 + ni * 16 + ll;
          const f32x4 v = acc[mh * 4 + mi][nh * 2 + ni];
          if (MODE == 0) {
            f16* C = (f16*)Cv;
#pragma unroll
            for (int rr = 0; rr < 4; rr++) C[(r0 + rr) * N + c] = (f16)v[rr];
          } else {
            float* C = (float*)Cv;
#pragma unroll
            for (int rr = 0; rr < 4; rr++) C[(r0 + rr) * N + c] = v[rr];
          }
        }
    }
}

// ------------- flash attention v3: 8 waves = 4 heads x 2 q-subtiles, defer-max -------------
__global__ __launch_bounds__(512) void attn_k3(const f16* __restrict__ Q,
                                               const f16* __restrict__ Kb,
                                               const f16* __restrict__ VT,
                                               f16* __restrict__ ctx) {
  __shared__ f16 Klds[2][64 * 128];   // 16 KB x2
  __shared__ f16 Vlds[2][128 * 64];   // 16 KB x2
  __shared__ f16 Plds[8][16 * 64];    // 2 KB/wave, XOR-swizzled (total LDS = 80 KB exactly)

  const int t = threadIdx.x, lane = t & 63, w = t >> 6;
  const int bid = blockIdx.x;
  // grid = 1024; 128 consecutive swz (= 2 (b,kvh) K/V sets = 2 MB) per XCD.
  const int swz = (bid & 7) * 128 + (bid >> 3);
  const int qt = swz & 63, kvh = (swz >> 6) & 7, b = swz >> 9;
  const int h = kvh * 4 + (w & 3);
  const int q0 = qt * 32 + (w >> 2) * 16;
  const int ll = lane & 15, lg = lane >> 4;

  const f16* Qb = Q + ((size_t)(b * SEQ + q0) * NH + h) * HD;
  const f16* Kh = Kb + ((size_t)b * SEQ * NKV + kvh) * HD;
  const f16* Vh = VT + ((size_t)(b * NKV + kvh)) * HD * SEQ;

  // Q A-fragments, prescaled by 1/sqrt(HD)*log2(e) so QK^T output is log2-domain.
  const float KSC2 = 0.08838834764831845f * 1.4426950408889634f;
  f16x8 qf[4];
#pragma unroll
  for (int kd = 0; kd < 4; kd++) {
    qf[kd] = *reinterpret_cast<const f16x8*>(Qb + (size_t)ll * (NH * HD) + kd * 32 + lg * 8);
#pragma unroll
    for (int j = 0; j < 8; j++) qf[kd][j] = (f16)((float)qf[kd][j] * KSC2);
  }

  float m_[4] = {-INFINITY, -INFINITY, -INFINITY, -INFINITY};
  float l_[4] = {0.f, 0.f, 0.f, 0.f};
  f32x4 o[8];
#pragma unroll
  for (int df = 0; df < 8; df++) o[df] = f32x4{0.f, 0.f, 0.f, 0.f};

  const float THR = 11.5416f;  // 8 nats in log2 units -> P bounded by e^8

  // stage K[64][128] + VT[128][64] tile at kt into buffer bufi (split over 8 waves).
  auto stage = [&](int bufi, int kt) {
#pragma unroll
    for (int rr = 0; rr < 2; rr++) {
      const int u = w * 128 + rr * 64 + lane;
      const int krow = u >> 4, klin = u & 15;
      const int kslot = klin ^ (krow & 7);
      const f16* ksrc = Kh + (size_t)(kt + krow) * (NKV * HD) + kslot * 8;
      __builtin_amdgcn_global_load_lds((const __attribute__((address_space(1))) void*)ksrc,
          (__attribute__((address_space(3))) void*)((char*)&Klds[bufi][0] + (size_t)(w * 128 + rr * 64) * 16),
          16, 0, 0);
      const int vrow = u >> 3, vlin = u & 7;
      const int vslot = vlin ^ (vrow & 7);
      const f16* vsrc = Vh + (size_t)vrow * SEQ + kt + vslot * 8;
      __builtin_amdgcn_global_load_lds((const __attribute__((address_space(1))) void*)vsrc,
          (__attribute__((address_space(3))) void*)((char*)&Vlds[bufi][0] + (size_t)(w * 128 + rr * 64) * 16),
          16, 0, 0);
    }
  };

  stage(0, 0);
  __syncthreads();

  for (int kt = 0; kt < SEQ; kt += 64) {
    const int buf = (kt >> 6) & 1;
    if (kt + 64 < SEQ) stage(buf ^ 1, kt + 64);

    const char* Kt = (const char*)Klds[buf];
    const char* Vt = (const char*)Vlds[buf];

    // S (log2-domain) = (ksc*log2e*Q) @ K^T
    f32x4 s[4];
#pragma unroll
    for (int nf = 0; nf < 4; nf++) {
      f32x4 a = f32x4{0.f, 0.f, 0.f, 0.f};
#pragma unroll
      for (int kd = 0; kd < 4; kd++) {
        const int row = nf * 16 + ll;
        f16x8 kf = *reinterpret_cast<const f16x8*>(
            Kt + row * 256 + ((((kd << 2) + lg) ^ (row & 7)) << 4));
        a = __builtin_amdgcn_mfma_f32_16x16x32_f16(qf[kd], kf, a, 0, 0, 0);
      }
      s[nf] = a;
    }

    // defer-max online softmax (T13). lane owns rows q = lg*4+r, col group ll.
    float mxl[4];
    bool okl = true;
#pragma unroll
    for (int r = 0; r < 4; r++) {
      mxl[r] = fmaxf(fmaxf(s[0][r], s[1][r]), fmaxf(s[2][r], s[3][r]));
      okl = okl && (mxl[r] <= m_[r] + THR);
    }
    if (!__all((int)okl)) {
      // full path: reduce max, rescale
#pragma unroll
      for (int r = 0; r < 4; r++) {
        float mx = mxl[r];
#pragma unroll
        for (int off = 1; off < 16; off <<= 1) mx = fmaxf(mx, __shfl_xor(mx, off, 64));
        const float mn = fmaxf(m_[r], mx);
        const float corr = __builtin_amdgcn_exp2f(m_[r] - mn);
        m_[r] = mn;
        l_[r] *= corr;
#pragma unroll
        for (int df = 0; df < 8; df++) o[df][r] *= corr;
      }
    }
#pragma unroll
    for (int r = 0; r < 4; r++) {
      float rs = 0.f;
#pragma unroll
      for (int nf = 0; nf < 4; nf++) {
        float p = __builtin_amdgcn_exp2f(s[nf][r] - m_[r]);
        s[nf][r] = p;
        rs += p;
      }
#pragma unroll
      for (int off = 1; off < 16; off <<= 1) rs += __shfl_xor(rs, off, 64);
      l_[r] += rs;
    }

    // P roundtrip via per-wave XOR-swizzled LDS [16 q][8 slots of 16B]
    char* Pw = (char*)&Plds[w][0];
#pragma unroll
    for (int nf = 0; nf < 4; nf++)
#pragma unroll
      for (int r = 0; r < 4; r++) {
        const int row = lg * 4 + r;
        const int slot = ((nf << 1) + (ll >> 3)) ^ (row & 7);
        *reinterpret_cast<f16*>(Pw + row * 128 + (slot << 4) + ((ll & 7) << 1)) = (f16)s[nf][r];
      }

    f16x8 pf[2];
#pragma unroll
    for (int kf = 0; kf < 2; kf++)
      pf[kf] = *reinterpret_cast<const f16x8*>(Pw + ll * 128 + ((((kf << 2) + lg) ^ (ll & 7)) << 4));

    // O += P @ V
#pragma unroll
    for (int kf = 0; kf < 2; kf++)
#pragma unroll
      for (int df = 0; df < 8; df++) {
        const int row = df * 16 + ll;
        f16x8 vf = *reinterpret_cast<const f16x8*>(
            Vt + row * 128 + ((((kf << 2) + lg) ^ (row & 7)) << 4));
        o[df] = __builtin_amdgcn_mfma_f32_16x16x32_f16(pf[kf], vf, o[df], 0, 0, 0);
      }

    __syncthreads();
  }

  float inv[4];
#pragma unroll
  for (int r = 0; r < 4; r++) inv[r] = 1.0f / l_[r];
  f16* cb = ctx + ((size_t)(b * SEQ + q0) * NH + h) * HD;
#pragma unroll
  for (int df = 0; df < 8; df++)
#pragma unroll
    for (int r = 0; r < 4; r++)
      cb[(size_t)(lg * 4 + r) * (NH * HD) + df * 16 + ll] = (f16)(o[df][r] * inv[r]);
}

extern "C" void kernel_launch(void* const* d_in, const int* in_sizes, int n_in,
                              void* d_out, int out_size, void* d_ws, size_t ws_size,
                              hipStream_t stream) {
  (void)in_sizes; (void)n_in; (void)out_size;
  const float* x  = (const float*)d_in[0];
  const float* wq = (const float*)d_in[1];
  const float* wk = (const float*)d_in[2];
  const float* wv = (const float*)d_in[3];
  const float* wo = (const float*)d_in[4];
  float* out = (float*)d_out;

  const size_t SZ_X  = (size_t)MTOK * DMODEL * sizeof(f16);
  const size_t SZ_KV = (size_t)MTOK * NKV * HD * sizeof(f16);
  if (ws_size < 3 * SZ_X + 2 * SZ_KV) return;

  char* ws = (char*)d_ws;
  f16* xh  = (f16*)ws;
  f16* wT  = (f16*)(ws + SZ_X);
  f16* Qb  = (f16*)(ws + 2 * SZ_X);
  f16* Kb  = (f16*)(ws + 3 * SZ_X);
  f16* VTb = (f16*)(ws + 3 * SZ_X + SZ_KV);

  cvt_f32_f16_k<<<dim3(MTOK * DMODEL / 8 / 256), 256, 0, stream>>>(x, xh, MTOK * DMODEL / 8);

  transpose_cvt_k<<<dim3(DMODEL / 32, DMODEL / 32), 256, 0, stream>>>(wq, wT, DMODEL, DMODEL);
  gemm256_k<0><<<dim3((MTOK / 256) * (DMODEL / 256)), 512, 0, stream>>>(xh, wT, Qb, MTOK, DMODEL, DMODEL);

  transpose_cvt_k<<<dim3(NKV * HD / 32, DMODEL / 32), 256, 0, stream>>>(wk, wT, DMODEL, NKV * HD);
  gemm_bt_k<0><<<dim3((MTOK / 128) * ((NKV * HD) / 128)), 256, 0, stream>>>(xh, wT, Kb, MTOK, NKV * HD, DMODEL);

  transpose_cvt_k<<<dim3(NKV * HD / 32, DMODEL / 32), 256, 0, stream>>>(wv, wT, DMODEL, NKV * HD);
  gemm_bt_k<1><<<dim3((MTOK / 128) * ((NKV * HD) / 128)), 256, 0, stream>>>(xh, wT, VTb, MTOK, NKV * HD, DMODEL);

  attn_k3<<<dim3(BATCH * NKV * (SEQ / 32)), 512, 0, stream>>>(Qb, Kb, VTb, xh);

  transpose_cvt_k<<<dim3(DMODEL / 32, DMODEL / 32), 256, 0, stream>>>(wo, wT, DMODEL, DMODEL);
  gemm256_k<2><<<dim3((MTOK / 256) * (DMODEL / 256)), 512, 0, stream>>>(xh, wT, out, MTOK, DMODEL, DMODEL);
}

// Round 4
// 615.319 us; speedup vs baseline: 2.4448x; 1.0662x over previous
//
#include <hip/hip_runtime.h>
#include <math.h>

typedef _Float16 f16;
using f16x8 = __attribute__((ext_vector_type(8))) _Float16;
using f32x4 = __attribute__((ext_vector_type(4))) float;

#define BATCH 2
#define SEQ   2048
#define DMODEL 4096
#define NH    32
#define NKV   8
#define HD    128
#define MTOK  (BATCH*SEQ)

// ---------------- f32 -> f16 convert ----------------
__global__ __launch_bounds__(256) void cvt_f32_f16_k(const float* __restrict__ in,
                                                     f16* __restrict__ out, int n8) {
  int i = blockIdx.x * 256 + threadIdx.x;
  if (i >= n8) return;
  const float4* p = reinterpret_cast<const float4*>(in) + (size_t)i * 2;
  float4 a = p[0], b = p[1];
  f16x8 o = { (f16)a.x, (f16)a.y, (f16)a.z, (f16)a.w,
              (f16)b.x, (f16)b.y, (f16)b.z, (f16)b.w };
  reinterpret_cast<f16x8*>(out)[i] = o;
}

// ------------- w[K][N] f32 -> wT[N][K] f16 -------------
__global__ __launch_bounds__(256) void transpose_cvt_k(const float* __restrict__ w,
                                                       f16* __restrict__ wt, int Kd, int Nd) {
  __shared__ float tile[32][33];
  const int t = threadIdx.x;
  const int n0 = blockIdx.x * 32, k0 = blockIdx.y * 32;
  const int r = t >> 3, c4 = (t & 7) << 2;
  const float4 v = *reinterpret_cast<const float4*>(w + (size_t)(k0 + r) * Nd + n0 + c4);
  tile[r][c4 + 0] = v.x; tile[r][c4 + 1] = v.y; tile[r][c4 + 2] = v.z; tile[r][c4 + 3] = v.w;
  __syncthreads();
  union { f16 h[4]; ushort4 u4; } pk;
  pk.h[0] = (f16)tile[c4 + 0][r];
  pk.h[1] = (f16)tile[c4 + 1][r];
  pk.h[2] = (f16)tile[c4 + 2][r];
  pk.h[3] = (f16)tile[c4 + 3][r];
  *reinterpret_cast<ushort4*>(wt + (size_t)(n0 + r) * Kd + k0 + c4) = pk.u4;
}

// ------------- 128^2 GEMM (K/V projections, N=1024) -------------
template<int MODE>
__global__ __launch_bounds__(256) void gemm_bt_k(const f16* __restrict__ A,
                                                 const f16* __restrict__ BT,
                                                 void* __restrict__ Cv,
                                                 int M, int N, int K) {
  __shared__ f16 Alds[128 * 64];
  __shared__ f16 Blds[128 * 64];
  const int t = threadIdx.x, lane = t & 63, w = t >> 6;
  const int nbn = N >> 7;
  const int nwg = gridDim.x;
  const int cpx = nwg >> 3;
  const int bid = blockIdx.x;
  const int swz = (bid & 7) * cpx + (bid >> 3);
  const int bm = swz / nbn, bn = swz % nbn;
  const size_t m0 = (size_t)bm << 7, n0 = (size_t)bn << 7;

  const int srow = t >> 3;
  const int sslot = t & 7;
  char* ldsAw = (char*)Alds + w * 1024;
  char* ldsBw = (char*)Blds + w * 1024;

  f32x4 acc[4][4];
#pragma unroll
  for (int i = 0; i < 4; i++)
#pragma unroll
    for (int j = 0; j < 4; j++) acc[i][j] = f32x4{0.f, 0.f, 0.f, 0.f};

  const int wr = (w >> 1) << 6, wc = (w & 1) << 6;
  const int ll = lane & 15, lg = lane >> 4;

  for (int kt = 0; kt < K; kt += 64) {
    __syncthreads();
#pragma unroll
    for (int p = 0; p < 4; p++) {
      const int row = srow + (p << 5);
      const int ssrc = (sslot ^ (row & 7)) << 3;
      const f16* gA = A + (m0 + row) * (size_t)K + kt + ssrc;
      __builtin_amdgcn_global_load_lds((const __attribute__((address_space(1))) void*)gA,
          (__attribute__((address_space(3))) void*)(ldsAw + p * 4096), 16, 0, 0);
      const f16* gB = BT + (n0 + row) * (size_t)K + kt + ssrc;
      __builtin_amdgcn_global_load_lds((const __attribute__((address_space(1))) void*)gB,
          (__attribute__((address_space(3))) void*)(ldsBw + p * 4096), 16, 0, 0);
    }
    __syncthreads();
#pragma unroll
    for (int kk = 0; kk < 2; kk++) {
      f16x8 af[4], bfr[4];
      const int slot = (kk << 2) + lg;
#pragma unroll
      for (int i = 0; i < 4; i++) {
        const int r = wr + (i << 4) + ll;
        af[i] = *reinterpret_cast<const f16x8*>((const char*)Alds + r * 128 + ((slot ^ (r & 7)) << 4));
      }
#pragma unroll
      for (int j = 0; j < 4; j++) {
        const int r = wc + (j << 4) + ll;
        bfr[j] = *reinterpret_cast<const f16x8*>((const char*)Blds + r * 128 + ((slot ^ (r & 7)) << 4));
      }
#pragma unroll
      for (int i = 0; i < 4; i++)
#pragma unroll
        for (int j = 0; j < 4; j++)
          acc[i][j] = __builtin_amdgcn_mfma_f32_16x16x32_f16(af[i], bfr[j], acc[i][j], 0, 0, 0);
    }
  }

#pragma unroll
  for (int i = 0; i < 4; i++) {
    const size_t mrow = m0 + wr + (i << 4) + (lg << 2);
#pragma unroll
    for (int j = 0; j < 4; j++) {
      const size_t ncol = n0 + wc + (j << 4) + ll;
      if (MODE == 0) {
        f16* C = (f16*)Cv;
#pragma unroll
        for (int r = 0; r < 4; r++) C[(mrow + r) * N + ncol] = (f16)acc[i][j][r];
      } else if (MODE == 1) {
        f16* C = (f16*)Cv;
        const int kvh = (int)(ncol >> 7), d = (int)(ncol & 127);
        const int b = (int)(mrow >> 11), s = (int)(mrow & 2047);
        union { f16 h[4]; ushort4 u4; } pk;
#pragma unroll
        for (int r = 0; r < 4; r++) pk.h[r] = (f16)acc[i][j][r];
        *reinterpret_cast<ushort4*>(C + (((size_t)(b * NKV + kvh) * HD + d) * SEQ + s)) = pk.u4;
      } else {
        float* C = (float*)Cv;
#pragma unroll
        for (int r = 0; r < 4; r++) C[(mrow + r) * N + ncol] = acc[i][j][r];
      }
    }
  }
}

// ------------- 256^2 8-phase GEMM (T2+T3+T4+T5) for the two 4096^3 GEMMs -------------
template<int MODE>
__global__ __launch_bounds__(512, 2) void gemm256_k(const f16* __restrict__ A,
                                                    const f16* __restrict__ BT,
                                                    void* __restrict__ Cv,
                                                    int M, int N, int K) {
  __shared__ f16 lds[2 * 4 * 128 * 64];   // 128 KB
  char* ldsb = (char*)lds;

  const int t = threadIdx.x, lane = t & 63, w = t >> 6;
  const int wm = w >> 2, wn = w & 3;
  const int ll = lane & 15, lg = lane >> 4;
  const int nbn = N >> 8;
  const int nwg = gridDim.x, cpx = nwg >> 3, bid = blockIdx.x;
  const int swz = (bid & 7) * cpx + (bid >> 3);
  const int bm = swz / nbn, bn = swz % nbn;
  const size_t m0 = (size_t)bm << 8, n0 = (size_t)bn << 8;
  const int NT = K >> 6;

  auto stage = [&](int bufI, int unit, int ktS) {
    const f16* base = (unit < 2) ? (A + (m0 + (size_t)(unit & 1) * 128) * (size_t)K)
                                 : (BT + (n0 + (size_t)(unit & 1) * 128) * (size_t)K);
#pragma unroll
    for (int rr = 0; rr < 2; rr++) {
      const int u = t + rr * 512;
      const int row = u >> 3, lin = u & 7;
      const int slot = lin ^ (row & 7);
      const f16* src = base + (size_t)row * K + ktS + slot * 8;
      char* dst = ldsb + (size_t)(bufI * 4 + unit) * 16384 + (size_t)(w * 64 + rr * 512) * 16;
      __builtin_amdgcn_global_load_lds((const __attribute__((address_space(1))) void*)src,
          (__attribute__((address_space(3))) void*)dst, 16, 0, 0);
    }
  };

  f32x4 acc[8][4];
#pragma unroll
  for (int i = 0; i < 8; i++)
#pragma unroll
    for (int j = 0; j < 4; j++) acc[i][j] = f32x4{0.f, 0.f, 0.f, 0.f};

  f16x8 af[4][2];
  f16x8 bfr[2][2][2];

  stage(0, 0, 0); stage(0, 2, 0); stage(0, 3, 0); stage(0, 1, 0);
  stage(1, 0, 64); stage(1, 2, 64); stage(1, 3, 64);
  asm volatile("s_waitcnt vmcnt(6)" ::: "memory");
  __builtin_amdgcn_sched_barrier(0);
  __builtin_amdgcn_s_barrier();

#define PH(RBUF, RDA, RDB, SBUF, SUNIT, STILE, VM, MH, NHQ) do {                          \
    if ((RDA) >= 0) {                                                                     \
      const char* ab = ldsb + (size_t)((RBUF) * 4 + (RDA)) * 16384;                       \
      _Pragma("unroll") for (int mi = 0; mi < 4; mi++)                                    \
        _Pragma("unroll") for (int kk = 0; kk < 2; kk++)                                  \
          af[mi][kk] = *reinterpret_cast<const f16x8*>(ab + (mi * 32 + wm * 16 + ll) * 128\
                               + ((((kk << 2) + lg) ^ (ll & 7)) << 4));                   \
    }                                                                                     \
    if ((RDB) >= 0) {                                                                     \
      const char* bb = ldsb + (size_t)((RBUF) * 4 + 2 + (RDB)) * 16384;                   \
      _Pragma("unroll") for (int ni = 0; ni < 2; ni++)                                    \
        _Pragma("unroll") for (int kk = 0; kk < 2; kk++)                                  \
          bfr[RDB][ni][kk] = *reinterpret_cast<const f16x8*>(bb +                         \
                               (wn * 32 + ni * 16 + ll) * 128                             \
                               + ((((kk << 2) + lg) ^ (ll & 7)) << 4));                   \
    }                                                                                     \
    stage((SBUF), (SUNIT), ((STILE) & (NT - 1)) << 6);                                    \
    if (VM) { asm volatile("s_waitcnt vmcnt(6)" ::: "memory");                            \
              __builtin_amdgcn_sched_barrier(0); }                                        \
    __builtin_amdgcn_s_barrier();                                                         \
    asm volatile("s_waitcnt lgkmcnt(0)" ::: "memory");                                    \
    __builtin_amdgcn_sched_barrier(0);                                                    \
    __builtin_amdgcn_s_setprio(1);                                                        \
    _Pragma("unroll") for (int kk = 0; kk < 2; kk++)                                      \
      _Pragma("unroll") for (int mi = 0; mi < 4; mi++)                                    \
        _Pragma("unroll") for (int ni = 0; ni < 2; ni++)                                  \
          acc[(MH) * 4 + mi][(NHQ) * 2 + ni] = __builtin_amdgcn_mfma_f32_16x16x32_f16(    \
              af[mi][kk], bfr[NHQ][ni][kk], acc[(MH) * 4 + mi][(NHQ) * 2 + ni], 0, 0, 0); \
    __builtin_amdgcn_s_setprio(0);                                                        \
    __builtin_amdgcn_s_barrier();                                                         \
  } while (0)

  for (int tt = 0; tt < NT; tt += 2) {
    PH(0,  0,  0, 1, 1, tt + 1, false, 0, 0);
    PH(0, -1,  1, 0, 0, tt + 2, false, 0, 1);
    PH(0,  1, -1, 0, 2, tt + 2, false, 1, 0);
    PH(0, -1, -1, 0, 3, tt + 2, true , 1, 1);
    PH(1,  0,  0, 0, 1, tt + 2, false, 0, 0);
    PH(1, -1,  1, 1, 0, tt + 3, false, 0, 1);
    PH(1,  1, -1, 1, 2, tt + 3, false, 1, 0);
    PH(1, -1, -1, 1, 3, tt + 3, true , 1, 1);
  }
#undef PH

#pragma unroll
  for (int mh = 0; mh < 2; mh++)
#pragma unroll
    for (int mi = 0; mi < 4; mi++) {
      const size_t r0 = m0 + mh * 128 + mi * 32 + wm * 16 + lg * 4;
#pragma unroll
      for (int nh = 0; nh < 2; nh++)
#pragma unroll
        for (int ni = 0; ni < 2; ni++) {
          const size_t c = n0 + nh * 128 + wn * 32 + ni * 16 + ll;
          const f32x4 v = acc[mh * 4 + mi][nh * 2 + ni];
          if (MODE == 0) {
            f16* C = (f16*)Cv;
#pragma unroll
            for (int rr = 0; rr < 4; rr++) C[(r0 + rr) * N + c] = (f16)v[rr];
          } else {
            float* C = (float*)Cv;
#pragma unroll
            for (int rr = 0; rr < 4; rr++) C[(r0 + rr) * N + c] = v[rr];
          }
        }
    }
}

// ------------- flash attention v4: swapped QK^T (S^T = K·Q^T), lane-local softmax -------------
// 8 waves = 4 heads x 2 q-subtiles. K[64][128], VT[128][64] LDS dbuf as before.
// S^T lane layout: kv = nf*16 + lg*4 + r, q = ll  ->  softmax reduce = 2 shfl_xor.
// P stored row-major [16 q][64 kv] (per-wave, XOR-swizzled): 4x ds_write_b64, 2x ds_read_b128.
__global__ __launch_bounds__(512) void attn_k4(const f16* __restrict__ Q,
                                               const f16* __restrict__ Kb,
                                               const f16* __restrict__ VT,
                                               f16* __restrict__ ctx) {
  __shared__ f16 Klds[2][64 * 128];   // 16 KB x2
  __shared__ f16 Vlds[2][128 * 64];   // 16 KB x2
  __shared__ f16 Plds[8][16 * 64];    // 2 KB/wave (total 80 KB)

  const int t = threadIdx.x, lane = t & 63, w = t >> 6;
  const int bid = blockIdx.x;
  const int swz = (bid & 7) * 128 + (bid >> 3);
  const int qt = swz & 63, kvh = (swz >> 6) & 7, b = swz >> 9;
  const int h = kvh * 4 + (w & 3);
  const int q0 = qt * 32 + (w >> 2) * 16;
  const int ll = lane & 15, lg = lane >> 4;

  const f16* Qb = Q + ((size_t)(b * SEQ + q0) * NH + h) * HD;
  const f16* Kh = Kb + ((size_t)b * SEQ * NKV + kvh) * HD;
  const f16* Vh = VT + ((size_t)(b * NKV + kvh)) * HD * SEQ;

  // Q fragments (used as MFMA *B* operand: col=q=ll, k = kd*32+lg*8+j), prescaled.
  const float KSC2 = 0.08838834764831845f * 1.4426950408889634f;
  f16x8 qf[4];
#pragma unroll
  for (int kd = 0; kd < 4; kd++) {
    qf[kd] = *reinterpret_cast<const f16x8*>(Qb + (size_t)ll * (NH * HD) + kd * 32 + lg * 8);
#pragma unroll
    for (int j = 0; j < 8; j++) qf[kd][j] = (f16)((float)qf[kd][j] * KSC2);
  }

  float m_ = -INFINITY;   // running max for q = ll (log2 domain)
  float l_ = 0.f;         // running sum for q = ll
  f32x4 o[8];
#pragma unroll
  for (int df = 0; df < 8; df++) o[df] = f32x4{0.f, 0.f, 0.f, 0.f};

  const float THR = 11.5416f;  // 8 nats in log2 units

  auto stage = [&](int bufi, int kt) {
#pragma unroll
    for (int rr = 0; rr < 2; rr++) {
      const int u = w * 128 + rr * 64 + lane;
      const int krow = u >> 4, klin = u & 15;
      const int kslot = klin ^ (krow & 7);
      const f16* ksrc = Kh + (size_t)(kt + krow) * (NKV * HD) + kslot * 8;
      __builtin_amdgcn_global_load_lds((const __attribute__((address_space(1))) void*)ksrc,
          (__attribute__((address_space(3))) void*)((char*)&Klds[bufi][0] + (size_t)(w * 128 + rr * 64) * 16),
          16, 0, 0);
      const int vrow = u >> 3, vlin = u & 7;
      const int vslot = vlin ^ (vrow & 7);
      const f16* vsrc = Vh + (size_t)vrow * SEQ + kt + vslot * 8;
      __builtin_amdgcn_global_load_lds((const __attribute__((address_space(1))) void*)vsrc,
          (__attribute__((address_space(3))) void*)((char*)&Vlds[bufi][0] + (size_t)(w * 128 + rr * 64) * 16),
          16, 0, 0);
    }
  };

  stage(0, 0);
  __syncthreads();

  for (int kt = 0; kt < SEQ; kt += 64) {
    const int buf = (kt >> 6) & 1;
    if (kt + 64 < SEQ) stage(buf ^ 1, kt + 64);

    const char* Kt = (const char*)Klds[buf];
    const char* Vt = (const char*)Vlds[buf];

    // S^T = (K) @ (scaled Q)^T : mfma(A=K-frag, B=Q-frag). Lane: kv=nf*16+lg*4+r, q=ll.
    f32x4 s[4];
#pragma unroll
    for (int nf = 0; nf < 4; nf++) {
      f32x4 a = f32x4{0.f, 0.f, 0.f, 0.f};
#pragma unroll
      for (int kd = 0; kd < 4; kd++) {
        const int row = nf * 16 + ll;
        f16x8 kf = *reinterpret_cast<const f16x8*>(
            Kt + row * 256 + ((((kd << 2) + lg) ^ (row & 7)) << 4));
        a = __builtin_amdgcn_mfma_f32_16x16x32_f16(kf, qf[kd], a, 0, 0, 0);
      }
      s[nf] = a;
    }

    // lane-local softmax for column q = ll (16 kv values per lane).
    float mx = s[0][0];
#pragma unroll
    for (int nf = 0; nf < 4; nf++)
#pragma unroll
      for (int r = 0; r < 4; r++) mx = fmaxf(mx, s[nf][r]);

    if (!__all((int)(mx <= m_ + THR))) {
      float mr = fmaxf(mx, __shfl_xor(mx, 16, 64));
      mr = fmaxf(mr, __shfl_xor(mr, 32, 64));
      const float mn = fmaxf(m_, mr);
      const float corrq = __builtin_amdgcn_exp2f(m_ - mn);
      m_ = mn;
      l_ *= corrq;
      // broadcast corr for O rows q' = lg*4+r from a lane with ll == q'
#pragma unroll
      for (int r = 0; r < 4; r++) {
        const float c = __shfl(corrq, (lane & 48) | (lg * 4 + r), 64);
#pragma unroll
        for (int df = 0; df < 8; df++) o[df][r] *= c;
      }
    }

    float rs = 0.f;
#pragma unroll
    for (int nf = 0; nf < 4; nf++)
#pragma unroll
      for (int r = 0; r < 4; r++) {
        const float p = __builtin_amdgcn_exp2f(s[nf][r] - m_);
        s[nf][r] = p;
        rs += p;
      }
    rs += __shfl_xor(rs, 16, 64);
    rs += __shfl_xor(rs, 32, 64);
    l_ += rs;

    // P row-major [16 q][64 kv] f16, XOR-swizzled 16B slots; lane writes its own row q=ll.
    char* Pw = (char*)&Plds[w][0];
#pragma unroll
    for (int nf = 0; nf < 4; nf++) {
      union { f16 h[4]; ushort4 u4; } pk;
#pragma unroll
      for (int r = 0; r < 4; r++) pk.h[r] = (f16)s[nf][r];
      *reinterpret_cast<ushort4*>(Pw + ll * 128 + ((nf * 32 + lg * 8) ^ ((ll & 7) << 4))) = pk.u4;
    }

    // PV A-frag: P[q=ll][kv = kf*32 + lg*8 + j] -> b128 from own row.
    f16x8 pf[2];
#pragma unroll
    for (int kf = 0; kf < 2; kf++)
      pf[kf] = *reinterpret_cast<const f16x8*>(Pw + ll * 128 + (((kf << 6) + (lg << 4)) ^ ((ll & 7) << 4)));

    // O += P @ V
#pragma unroll
    for (int kf = 0; kf < 2; kf++)
#pragma unroll
      for (int df = 0; df < 8; df++) {
        const int row = df * 16 + ll;
        f16x8 vf = *reinterpret_cast<const f16x8*>(
            Vt + row * 128 + ((((kf << 2) + lg) ^ (row & 7)) << 4));
        o[df] = __builtin_amdgcn_mfma_f32_16x16x32_f16(pf[kf], vf, o[df], 0, 0, 0);
      }

    __syncthreads();
  }

  // final: O row q' = lg*4+r needs l_ from a lane with ll == q'
  float inv[4];
#pragma unroll
  for (int r = 0; r < 4; r++) {
    const float lq = __shfl(l_, (lane & 48) | (lg * 4 + r), 64);
    inv[r] = 1.0f / lq;
  }
  f16* cb = ctx + ((size_t)(b * SEQ + q0) * NH + h) * HD;
#pragma unroll
  for (int df = 0; df < 8; df++)
#pragma unroll
    for (int r = 0; r < 4; r++)
      cb[(size_t)(lg * 4 + r) * (NH * HD) + df * 16 + ll] = (f16)(o[df][r] * inv[r]);
}

extern "C" void kernel_launch(void* const* d_in, const int* in_sizes, int n_in,
                              void* d_out, int out_size, void* d_ws, size_t ws_size,
                              hipStream_t stream) {
  (void)in_sizes; (void)n_in; (void)out_size;
  const float* x  = (const float*)d_in[0];
  const float* wq = (const float*)d_in[1];
  const float* wk = (const float*)d_in[2];
  const float* wv = (const float*)d_in[3];
  const float* wo = (const float*)d_in[4];
  float* out = (float*)d_out;

  const size_t SZ_X  = (size_t)MTOK * DMODEL * sizeof(f16);
  const size_t SZ_KV = (size_t)MTOK * NKV * HD * sizeof(f16);
  if (ws_size < 3 * SZ_X + 2 * SZ_KV) return;

  char* ws = (char*)d_ws;
  f16* xh  = (f16*)ws;
  f16* wT  = (f16*)(ws + SZ_X);
  f16* Qb  = (f16*)(ws + 2 * SZ_X);
  f16* Kb  = (f16*)(ws + 3 * SZ_X);
  f16* VTb = (f16*)(ws + 3 * SZ_X + SZ_KV);

  cvt_f32_f16_k<<<dim3(MTOK * DMODEL / 8 / 256), 256, 0, stream>>>(x, xh, MTOK * DMODEL / 8);

  transpose_cvt_k<<<dim3(DMODEL / 32, DMODEL / 32), 256, 0, stream>>>(wq, wT, DMODEL, DMODEL);
  gemm256_k<0><<<dim3((MTOK / 256) * (DMODEL / 256)), 512, 0, stream>>>(xh, wT, Qb, MTOK, DMODEL, DMODEL);

  transpose_cvt_k<<<dim3(NKV * HD / 32, DMODEL / 32), 256, 0, stream>>>(wk, wT, DMODEL, NKV * HD);
  gemm_bt_k<0><<<dim3((MTOK / 128) * ((NKV * HD) / 128)), 256, 0, stream>>>(xh, wT, Kb, MTOK, NKV * HD, DMODEL);

  transpose_cvt_k<<<dim3(NKV * HD / 32, DMODEL / 32), 256, 0, stream>>>(wv, wT, DMODEL, NKV * HD);
  gemm_bt_k<1><<<dim3((MTOK / 128) * ((NKV * HD) / 128)), 256, 0, stream>>>(xh, wT, VTb, MTOK, NKV * HD, DMODEL);

  attn_k4<<<dim3(BATCH * NKV * (SEQ / 32)), 512, 0, stream>>>(Qb, Kb, VTb, xh);

  transpose_cvt_k<<<dim3(DMODEL / 32, DMODEL / 32), 256, 0, stream>>>(wo, wT, DMODEL, DMODEL);
  gemm256_k<2><<<dim3((MTOK / 256) * (DMODEL / 256)), 512, 0, stream>>>(xh, wT, out, MTOK, DMODEL, DMODEL);
}